// Round 15
// baseline (173.312 us; speedup 1.0000x reference)
//
#include <hip/hip_runtime.h>

// Problem constants
#define B_    1024
#define C_    128
#define ELL   16
#define EQ    3
#define E_    10
#define P3    23
#define P2    5
#define NSEG  176            // padded segment row: 16 f4-aligned v-segments
#define RSTR  180            // Sg row stride
#define SRS   (48 * RSTR)    // 8640 floats per (e,c) S-slice
#define KD    28             // folded weight depth: 23 (wmax) + 5 (w2)

// MFMA geometry (k_main r26)
#define MROWS 128            // padded bucket rows per chunk
#define KSL   64             // K-slice width; 3 slices cover 192 >= NSEG
#define FSTR  72             // bf16 row stride: 144B = 36 banks = 4 mod 32
                             // -> 8 distinct 4-bank span starts -> conflict-free
                             //    b128 reads; 144 % 16 == 0 keeps 16B alignment.

typedef float v2f __attribute__((ext_vector_type(2)));
using short8 = __attribute__((ext_vector_type(8))) short;   // 8 bf16 (4 VGPR)
using f32x4  = __attribute__((ext_vector_type(4))) float;   // MFMA C/D

// segment offsets: v-th segment holds [lin_v, Q_vv, Q_v,v+1, .., Q_v,15, pad0s]
#define SEG_OFF_INIT {0,20,36,52,68,84,96,108,120,132,140,148,156,164,168,172}

// ---------------------------------------------------------------------------
// bf16 split (round-to-nearest-even): f = hi + lo with |lo| <= ulp(hi)/2.
// Product f*g = hi_f*hi_g + hi_f*lo_g + lo_f*hi_g (+ lo*lo ~ 2^-32, dropped).
__device__ __forceinline__ unsigned short bf16_rne(float f) {
    unsigned int u = __float_as_uint(f);
    unsigned int lsb = (u >> 16) & 1u;
    return (unsigned short)((u + 0x7fffu + lsb) >> 16);
}
__device__ __forceinline__ float bf16_to_f(unsigned short h) {
    return __uint_as_float(((unsigned int)h) << 16);
}

// DPP row_ror add chain: width-16 sum-to-all within each 16-lane DPP row.
// VERIFIED r18b-r25. Sums over lane&15 (= xx) for fixed lane>>4.
template <int CTRL>
__device__ __forceinline__ float dpp_ror_add(float v) {
    int s = __float_as_int(v);
    int r = __builtin_amdgcn_update_dpp(s, s, CTRL, 0xF, 0xF, false);
    return v + __int_as_float(r);
}
__device__ __forceinline__ float row16_sum(float v) {
    v = dpp_ror_add<0x121>(v);
    v = dpp_ror_add<0x122>(v);
    v = dpp_ror_add<0x124>(v);
    v = dpp_ror_add<0x128>(v);
    return v;
}

// ---------------------------------------------------------------------------
// Bucketing: pad each bucket to x128 (r18b-verified version; k_main r26
// consumes 128-row chunks with no load guards).
__device__ void do_lists(const float* __restrict__ y, int* __restrict__ cnt_g,
                         int* __restrict__ list_g, int t) {
    __shared__ int lcnt[E_];
    if (t < E_) lcnt[t] = 0;
    __syncthreads();
    for (int r = 0; r < 4; ++r) {
        int b = t + 256 * r;
        int e = 0;
        #pragma unroll
        for (int j = 1; j < E_; ++j)
            if (y[b * E_ + j] > 0.5f) e = j;
        int slot = atomicAdd(&lcnt[e], 1);
        list_g[e * B_ + slot] = b;
    }
    __syncthreads();
    if (t < E_) {
        int c0 = lcnt[t];
        cnt_g[t] = c0;
        int last = (c0 > 0) ? list_g[t * B_ + c0 - 1] : 0;
        int cp = (c0 + 127) & ~127;
        if (cp > B_) cp = B_;
        for (int s2 = c0; s2 < cp; ++s2) list_g[t * B_ + s2] = last;
    }
}

// ---------------------------------------------------------------------------
// k_s r26 = EXACT r17 (verified win). Unchanged.
__global__ __launch_bounds__(256, 2) void k_s(const float* __restrict__ U3,
                                              const float* __restrict__ U2,
                                              const float* __restrict__ wmax,
                                              const float* __restrict__ w2,
                                              const float* __restrict__ y,
                                              float* __restrict__ Sg,
                                              int* __restrict__ cnt_g,
                                              int* __restrict__ list_g) {
    const int t = threadIdx.x;
    if (blockIdx.x == 48) {
        if (blockIdx.y == 0 && blockIdx.z == 0) do_lists(y, cnt_g, list_g, t);
        return;
    }
    __shared__ __align__(16) float wsm[KD * 32];          //  3,584 B
    __shared__ __align__(16) float SKL[NSEG * KD];        // 19,712 B

    const int j  = blockIdx.x;
    const int e  = blockIdx.y;
    const int cq = blockIdx.z;

    for (int idx = t; idx < KD * 32; idx += 256) {
        int k = idx >> 5, cc = idx & 31, c = cq * 32 + cc;
        wsm[idx] = (k < 23) ? wmax[(e * P3 + k) * C_ + c]
                            : w2[(e * P2 + (k - 23)) * C_ + c];
    }

    if (t < NSEG) {
        const int SO[16] = SEG_OFF_INIT;
        int v = 0;
        #pragma unroll
        for (int s = 1; s < 16; ++s) v += (t >= SO[s]) ? 1 : 0;
        const int l    = t - SO[v];
        const int real = 17 - v;

        float row[KD];
        #pragma unroll
        for (int d = 0; d < KD; ++d) row[d] = 0.f;

        if (l == 0) {
            #pragma unroll
            for (int q = 0; q < P2; ++q)
                row[23 + q] = U2[(size_t)j * (ELL * P2) + v * P2 + q];
        } else if (l < real) {
            int i = v + l - 1;
            const float* pa = U3 + (size_t)j * (ELL * ELL * P3) + (v * ELL + i) * P3;
            const float* pb = U3 + (size_t)j * (ELL * ELL * P3) + (i * ELL + v) * P3;
            if (i != v) {
                #pragma unroll
                for (int k = 0; k < P3; ++k) row[k] = pa[k] + pb[k];
            } else {
                #pragma unroll
                for (int k = 0; k < P3; ++k) row[k] = pa[k];
            }
        }

        float* dst = &SKL[t * KD];
        #pragma unroll
        for (int d4 = 0; d4 < KD / 4; ++d4)
            *(float4*)(dst + 4 * d4) = make_float4(row[4 * d4], row[4 * d4 + 1],
                                                   row[4 * d4 + 2], row[4 * d4 + 3]);
    }
    __syncthreads();

    if (t >= NSEG) return;

    const int sg = t % 44;
    const int cg = t / 44;
    const int c8 = cg * 8;

    v2f acc[4][4];
    #pragma unroll
    for (int s = 0; s < 4; ++s)
        #pragma unroll
        for (int cp2 = 0; cp2 < 4; ++cp2) acc[s][cp2] = (v2f){0.f, 0.f};

    #pragma unroll
    for (int k4 = 0; k4 < KD / 4; ++k4) {
        float4 sk4[4];
        #pragma unroll
        for (int s = 0; s < 4; ++s)
            sk4[s] = *(const float4*)&SKL[(sg + 44 * s) * KD + 4 * k4];
        #pragma unroll
        for (int kk = 0; kk < 4; ++kk) {
            const int k = 4 * k4 + kk;
            float4 w0 = *(const float4*)&wsm[k * 32 + c8];
            float4 w1 = *(const float4*)&wsm[k * 32 + c8 + 4];
            v2f wp0 = {w0.x, w0.y}, wp1 = {w0.z, w0.w};
            v2f wp2 = {w1.x, w1.y}, wp3 = {w1.z, w1.w};
            #pragma unroll
            for (int s = 0; s < 4; ++s) {
                const float skv = (kk == 0) ? sk4[s].x : (kk == 1) ? sk4[s].y
                                : (kk == 2) ? sk4[s].z : sk4[s].w;
                acc[s][0] += skv * wp0;
                acc[s][1] += skv * wp1;
                acc[s][2] += skv * wp2;
                acc[s][3] += skv * wp3;
            }
        }
    }

    #pragma unroll
    for (int s = 0; s < 4; ++s) {
        const int slot = sg + 44 * s;
        #pragma unroll
        for (int cc = 0; cc < 8; ++cc) {
            const int c = cq * 32 + c8 + cc;
            Sg[(size_t)(e * C_ + c) * SRS + j * RSTR + slot] = acc[s][cc >> 1][cc & 1];
        }
    }
}

// ---------------------------------------------------------------------------
// k_main r26: MFMA reformulation. Per (e,c): OUT[128,48] = F[128,192]*S^T,
//   F[b, slot(v,0)]   = x_v           (multiplies lin_v)
//   F[b, slot(v,l>0)] = x_v * x_i     (multiplies symmetrized Q_vi)
// K=192 in 3 slices of 64; bf16 hi/lo split -> 3 MFMA terms (AhBh+AhBl+AlBh,
// lo*lo ~ 2^-32 dropped). Layout facts (guide-verified): C/D col=lane&15,
// row=(lane>>4)*4+reg (m89); A row=lane&15 / B col=lane&15, k=(lane>>4)*8+e
// (m156 tr-read corroborates). Epilogue: lane holds (b=row, xx=lane&15, w=n);
// cv = (D + U1[w*16+xx]*w1ec) * x[b][xx]; row16_sum over lane&15 = the xx
// contraction (identical tree to the verified DPP tail); lane&15==0 stores.
// Rationale: 12 variants pinned scalar k_main at 42+/-3us = VALU-issue floor
// at sustained clock; matrix pipe is idle (MfmaUtil 0 all session). Issue
// model here: ~2.5K VALU + ~530 LDS + 108 MFMA cy/wave -> ~15-25us.
__global__ __launch_bounds__(256, 2) void k_main(
    const float* __restrict__ x, const float* __restrict__ Sg,
    const float* __restrict__ U1, const float* __restrict__ w1,
    const int* __restrict__ cnt_g, const int* __restrict__ list_g,
    float* __restrict__ out) {

    __shared__ __align__(16) unsigned short Fh[MROWS * FSTR];  // 18,432 B
    __shared__ __align__(16) unsigned short Fl[MROWS * FSTR];  // 18,432 B
    __shared__ __align__(16) unsigned short Sh[48 * FSTR];     //  6,912 B
    __shared__ __align__(16) unsigned short Sl[48 * FSTR];     //  6,912 B
    __shared__ __align__(16) float XL[MROWS * ELL];            //  8,192 B
    // total 58,880 B -> 2 blocks/CU

    const int t    = threadIdx.x;
    const int c    = blockIdx.x;
    const int e    = blockIdx.y;
    const int lane = t & 63;
    const int wv   = t >> 6;           // wave 0..3
    const int lr   = lane & 15;        // A-row / B-col / D-col (xx)
    const int lq   = lane >> 4;        // 0..3
    const int cnt  = cnt_g[e];
    const int cntp = (cnt + 127) & ~127;
    const float w1ec = w1[e * C_ + c];
    const float* sgbase = Sg + (size_t)(e * C_ + c) * SRS;
    const int SO[16] = SEG_OFF_INIT;

    // F-build slot metadata (thread owns one slot column per slice)
    const int sl = t & 63;             // k-local 0..63
    const int rg = t >> 6;             // row group 0..3 (32 rows each)

    for (int base = 0; base < cntp; base += MROWS) {
        if (base > 0) __syncthreads();   // protect XL/F/S vs prev chunk reads

        // ---- stage X: rows base..base+127 (list_g padded x128, no guards)
        if (t < MROWS) {
            const int b = list_g[e * B_ + base + t];
            const float* xb = x + ((size_t)b * C_ + c) * ELL;
            float4* dst = (float4*)&XL[t * ELL];
            #pragma unroll
            for (int i4 = 0; i4 < 4; ++i4) dst[i4] = ((const float4*)xb)[i4];
        }
        __syncthreads();

        f32x4 acc[6];
        #pragma unroll
        for (int ti = 0; ti < 6; ++ti) acc[ti] = (f32x4){0.f, 0.f, 0.f, 0.f};

        for (int ks = 0; ks < 3; ++ks) {
            if (ks > 0) __syncthreads();   // prev GEMM done reading F/S

            // ---- build F slice: slot = ks*64 + sl, rows rg*32..+31
            {
                const int slot = ks * KSL + sl;
                int v = 0;
                #pragma unroll
                for (int s = 1; s < 16; ++s) v += (slot >= SO[s]) ? 1 : 0;
                const int l    = slot - SO[v];
                const int real = 17 - v;
                const bool is_lin = (slot < NSEG) && (l == 0);
                const bool is_q   = (slot < NSEG) && (l > 0) && (l < real);
                const int  isafe  = is_q ? (v + l - 1) : 0;
                #pragma unroll 4
                for (int rr = 0; rr < 32; ++rr) {
                    const int row = rg * 32 + rr;
                    const float xv = XL[row * ELL + v];
                    const float xi = XL[row * ELL + isafe];
                    const float f  = is_lin ? xv : (is_q ? xv * xi : 0.f);
                    const unsigned short h = bf16_rne(f);
                    Fh[row * FSTR + sl] = h;
                    Fl[row * FSTR + sl] = bf16_rne(f - bf16_to_f(h));
                }
            }
            // ---- build S slice: 48 x 64 entries, 12/thread, coalesced reads
            {
                #pragma unroll 4
                for (int j2 = 0; j2 < 12; ++j2) {
                    const int ei = t + 256 * j2;       // 0..3071
                    const int n  = ei >> 6;            // 0..47 (= w*16+xx)
                    const int kl = ei & 63;
                    const int slot2 = ks * KSL + kl;
                    const float sv = (slot2 < NSEG) ? sgbase[n * RSTR + slot2]
                                                    : 0.f;
                    const unsigned short h = bf16_rne(sv);
                    Sh[n * FSTR + kl] = h;
                    Sl[n * FSTR + kl] = bf16_rne(sv - bf16_to_f(h));
                }
            }
            __syncthreads();

            // ---- GEMM: 24 tiles (8m x 3n), wave wv owns {wv, wv+4, ...}
            #pragma unroll
            for (int ti = 0; ti < 6; ++ti) {
                const int tile = wv + 4 * ti;
                const int m = tile / 3;
                const int n = tile % 3;
                const unsigned short* fah = &Fh[(m * 16 + lr) * FSTR];
                const unsigned short* fal = &Fl[(m * 16 + lr) * FSTR];
                const unsigned short* fbh = &Sh[(n * 16 + lr) * FSTR];
                const unsigned short* fbl = &Sl[(n * 16 + lr) * FSTR];
                #pragma unroll
                for (int kst = 0; kst < 2; ++kst) {
                    const int ko = kst * 32 + lq * 8;
                    short8 ah = *(const short8*)(fah + ko);
                    short8 al = *(const short8*)(fal + ko);
                    short8 bh = *(const short8*)(fbh + ko);
                    short8 bl = *(const short8*)(fbl + ko);
                    acc[ti] = __builtin_amdgcn_mfma_f32_16x16x32_bf16(
                                  ah, bh, acc[ti], 0, 0, 0);
                    acc[ti] = __builtin_amdgcn_mfma_f32_16x16x32_bf16(
                                  ah, bl, acc[ti], 0, 0, 0);
                    acc[ti] = __builtin_amdgcn_mfma_f32_16x16x32_bf16(
                                  al, bh, acc[ti], 0, 0, 0);
                }
            }
        }

        // ---- epilogue: xx-contraction via verified DPP tree
        #pragma unroll
        for (int ti = 0; ti < 6; ++ti) {
            const int tile = wv + 4 * ti;
            const int m = tile / 3;
            const int n = tile % 3;
            const float v1x = U1[n * 16 + lr] * w1ec;
            #pragma unroll
            for (int reg = 0; reg < 4; ++reg) {
                const int row = m * 16 + lq * 4 + reg;
                const float xmv = XL[row * ELL + lr];
                float cv = (acc[ti][reg] + v1x) * xmv;
                cv = row16_sum(cv);
                if (lr == 0) {
                    const int gslot = base + row;
                    if (gslot < cnt) {
                        const int b = list_g[e * B_ + gslot];
                        out[(size_t)b * (C_ * EQ) + c * EQ + n] = cv;
                    }
                }
            }
        }
    }
}

// ---------------------------------------------------------------------------
extern "C" void kernel_launch(void* const* d_in, const int* in_sizes, int n_in,
                              void* d_out, int out_size, void* d_ws, size_t ws_size,
                              hipStream_t stream) {
    const float* x    = (const float*)d_in[0];
    const float* y    = (const float*)d_in[1];
    const float* U3   = (const float*)d_in[2];
    const float* U2   = (const float*)d_in[3];
    const float* U1   = (const float*)d_in[4];
    const float* wmax = (const float*)d_in[5];
    const float* w2   = (const float*)d_in[6];
    const float* w1   = (const float*)d_in[7];
    float* out = (float*)d_out;
    char*  ws  = (char*)d_ws;

    int*   cnt_g  = (int*)(ws + 0);
    int*   list_g = (int*)(ws + 64);
    float* Sg     = (float*)(ws + 65536);
    (void)ws_size;   // 44.3 MB needed; harness ws confirmed >= 66 MB

    k_s<<<dim3(49, E_, 4), 256, 0, stream>>>(U3, U2, wmax, w2, y, Sg, cnt_g, list_g);
    k_main<<<dim3(C_, E_), 256, 0, stream>>>(x, Sg, U1, w1, cnt_g, list_g, out);
}

// Round 16
// 123.053 us; speedup vs baseline: 1.4084x; 1.4084x over previous
//
#include <hip/hip_runtime.h>

// Problem constants
#define B_    1024
#define C_    128
#define ELL   16
#define EQ    3
#define E_    10
#define P3    23
#define P2    5
#define NSEG  176            // real segment slots; K padded to 192
#define RSTR  180            // Sg row stride (floats)
#define SRS   (48 * RSTR)    // 8640 floats per (e,c) S-slice
#define KD    28             // folded weight depth: 23 (wmax) + 5 (w2)

// MFMA geometry (k_main r27)
#define MROWS 128            // padded bucket rows per chunk
#define KSL   64             // K-slice width; 3 slices cover 192
#define FSTRB 128            // bf16 row stride in BYTES (64 shorts, pow2 + swizzle)
// XOR swizzle (guide G4): spreads pow2 row stride across 8 LDS spans.
#define SWZ(row, byteoff) ((byteoff) ^ (((row) & 7) << 4))

typedef float v2f __attribute__((ext_vector_type(2)));
using short8 = __attribute__((ext_vector_type(8))) short;   // 8 bf16
using f32x4  = __attribute__((ext_vector_type(4))) float;   // MFMA C/D

#define SEG_OFF_INIT {0,20,36,52,68,84,96,108,120,132,140,148,156,164,168,172}

// ---------------------------------------------------------------------------
// bf16 split (RNE): f = hi + lo. Product via AhBh+AhBl+AlBh (lo*lo dropped).
// VERIFIED r26 (passed, absmax 0.03125).
__device__ __forceinline__ unsigned short bf16_rne(float f) {
    unsigned int u = __float_as_uint(f);
    unsigned int lsb = (u >> 16) & 1u;
    return (unsigned short)((u + 0x7fffu + lsb) >> 16);
}
__device__ __forceinline__ float bf16_to_f(unsigned short h) {
    return __uint_as_float(((unsigned int)h) << 16);
}

// DPP row_ror width-16 sum-to-all. VERIFIED r18b-r26.
template <int CTRL>
__device__ __forceinline__ float dpp_ror_add(float v) {
    int s = __float_as_int(v);
    int r = __builtin_amdgcn_update_dpp(s, s, CTRL, 0xF, 0xF, false);
    return v + __int_as_float(r);
}
__device__ __forceinline__ float row16_sum(float v) {
    v = dpp_ror_add<0x121>(v);
    v = dpp_ror_add<0x122>(v);
    v = dpp_ror_add<0x124>(v);
    v = dpp_ror_add<0x128>(v);
    return v;
}

// ---------------------------------------------------------------------------
// Bucketing: pad to x128 (r18b/r26-verified).
__device__ void do_lists(const float* __restrict__ y, int* __restrict__ cnt_g,
                         int* __restrict__ list_g, int t) {
    __shared__ int lcnt[E_];
    if (t < E_) lcnt[t] = 0;
    __syncthreads();
    for (int r = 0; r < 4; ++r) {
        int b = t + 256 * r;
        int e = 0;
        #pragma unroll
        for (int j = 1; j < E_; ++j)
            if (y[b * E_ + j] > 0.5f) e = j;
        int slot = atomicAdd(&lcnt[e], 1);
        list_g[e * B_ + slot] = b;
    }
    __syncthreads();
    if (t < E_) {
        int c0 = lcnt[t];
        cnt_g[t] = c0;
        int last = (c0 > 0) ? list_g[t * B_ + c0 - 1] : 0;
        int cp = (c0 + 127) & ~127;
        if (cp > B_) cp = B_;
        for (int s2 = c0; s2 < cp; ++s2) list_g[t * B_ + s2] = last;
    }
}

// ---------------------------------------------------------------------------
// k_s = EXACT r17 (verified win). Unchanged.
__global__ __launch_bounds__(256, 2) void k_s(const float* __restrict__ U3,
                                              const float* __restrict__ U2,
                                              const float* __restrict__ wmax,
                                              const float* __restrict__ w2,
                                              const float* __restrict__ y,
                                              float* __restrict__ Sg,
                                              int* __restrict__ cnt_g,
                                              int* __restrict__ list_g) {
    const int t = threadIdx.x;
    if (blockIdx.x == 48) {
        if (blockIdx.y == 0 && blockIdx.z == 0) do_lists(y, cnt_g, list_g, t);
        return;
    }
    __shared__ __align__(16) float wsm[KD * 32];
    __shared__ __align__(16) float SKL[NSEG * KD];

    const int j  = blockIdx.x;
    const int e  = blockIdx.y;
    const int cq = blockIdx.z;

    for (int idx = t; idx < KD * 32; idx += 256) {
        int k = idx >> 5, cc = idx & 31, c = cq * 32 + cc;
        wsm[idx] = (k < 23) ? wmax[(e * P3 + k) * C_ + c]
                            : w2[(e * P2 + (k - 23)) * C_ + c];
    }

    if (t < NSEG) {
        const int SO[16] = SEG_OFF_INIT;
        int v = 0;
        #pragma unroll
        for (int s = 1; s < 16; ++s) v += (t >= SO[s]) ? 1 : 0;
        const int l    = t - SO[v];
        const int real = 17 - v;

        float row[KD];
        #pragma unroll
        for (int d = 0; d < KD; ++d) row[d] = 0.f;

        if (l == 0) {
            #pragma unroll
            for (int q = 0; q < P2; ++q)
                row[23 + q] = U2[(size_t)j * (ELL * P2) + v * P2 + q];
        } else if (l < real) {
            int i = v + l - 1;
            const float* pa = U3 + (size_t)j * (ELL * ELL * P3) + (v * ELL + i) * P3;
            const float* pb = U3 + (size_t)j * (ELL * ELL * P3) + (i * ELL + v) * P3;
            if (i != v) {
                #pragma unroll
                for (int k = 0; k < P3; ++k) row[k] = pa[k] + pb[k];
            } else {
                #pragma unroll
                for (int k = 0; k < P3; ++k) row[k] = pa[k];
            }
        }

        float* dst = &SKL[t * KD];
        #pragma unroll
        for (int d4 = 0; d4 < KD / 4; ++d4)
            *(float4*)(dst + 4 * d4) = make_float4(row[4 * d4], row[4 * d4 + 1],
                                                   row[4 * d4 + 2], row[4 * d4 + 3]);
    }
    __syncthreads();

    if (t >= NSEG) return;

    const int sg = t % 44;
    const int cg = t / 44;
    const int c8 = cg * 8;

    v2f acc[4][4];
    #pragma unroll
    for (int s = 0; s < 4; ++s)
        #pragma unroll
        for (int cp2 = 0; cp2 < 4; ++cp2) acc[s][cp2] = (v2f){0.f, 0.f};

    #pragma unroll
    for (int k4 = 0; k4 < KD / 4; ++k4) {
        float4 sk4[4];
        #pragma unroll
        for (int s = 0; s < 4; ++s)
            sk4[s] = *(const float4*)&SKL[(sg + 44 * s) * KD + 4 * k4];
        #pragma unroll
        for (int kk = 0; kk < 4; ++kk) {
            const int k = 4 * k4 + kk;
            float4 w0 = *(const float4*)&wsm[k * 32 + c8];
            float4 w1 = *(const float4*)&wsm[k * 32 + c8 + 4];
            v2f wp0 = {w0.x, w0.y}, wp1 = {w0.z, w0.w};
            v2f wp2 = {w1.x, w1.y}, wp3 = {w1.z, w1.w};
            #pragma unroll
            for (int s = 0; s < 4; ++s) {
                const float skv = (kk == 0) ? sk4[s].x : (kk == 1) ? sk4[s].y
                                : (kk == 2) ? sk4[s].z : sk4[s].w;
                acc[s][0] += skv * wp0;
                acc[s][1] += skv * wp1;
                acc[s][2] += skv * wp2;
                acc[s][3] += skv * wp3;
            }
        }
    }

    #pragma unroll
    for (int s = 0; s < 4; ++s) {
        const int slot = sg + 44 * s;
        #pragma unroll
        for (int cc = 0; cc < 8; ++cc) {
            const int c = cq * 32 + c8 + cc;
            Sg[(size_t)(e * C_ + c) * SRS + j * RSTR + slot] = acc[s][cc >> 1][cc & 1];
        }
    }
}

// ---------------------------------------------------------------------------
// build_F<KS,HALF>: this thread's row, 32 compile-time slots -> packed b128.
// Compile-time slot => compile-time (v, i, mode) => static xr[] indexing
// (rule #20) and folded SO-chain. 8 LDS writes/slice vs r26's 128 ops.
template <int KS, int HALF>
__device__ __forceinline__ void build_F(const float (&xr)[16], int row,
                                        unsigned short* __restrict__ Fh,
                                        unsigned short* __restrict__ Fl) {
    const int SO[16] = SEG_OFF_INIT;
    #pragma unroll
    for (int g = 0; g < 4; ++g) {
        short8 hi, lo;
        #pragma unroll
        for (int j8 = 0; j8 < 8; ++j8) {
            const int slot = KS * KSL + HALF * 32 + g * 8 + j8;   // CT
            int v = 0;
            #pragma unroll
            for (int s = 1; s < 16; ++s) v += (slot >= SO[s]) ? 1 : 0;
            const int l    = slot - SO[v];
            const int real = 17 - v;
            const bool is_lin = (slot < NSEG) && (l == 0);
            const bool is_q   = (slot < NSEG) && (l > 0) && (l < real);
            const int  iq     = is_q ? (v + l - 1) : 0;
            const float f = is_lin ? xr[v] : (is_q ? xr[v] * xr[iq] : 0.f);
            const unsigned short h = bf16_rne(f);
            hi[j8] = (short)h;
            lo[j8] = (short)bf16_rne(f - bf16_to_f(h));
        }
        const int off = SWZ(row, HALF * 64 + g * 16);
        *(short8*)((char*)Fh + row * FSTRB + off) = hi;
        *(short8*)((char*)Fl + row * FSTRB + off) = lo;
    }
}

// ---------------------------------------------------------------------------
// k_main r27: MFMA (r26 math, verified) with the three fixes from r26's PMC:
//  1. F-build row-ownership + packed b128 writes (LDS instrs /10)
//  2. GEMM wave retile 2m x 3n, A hoisted per kst (48 -> 20 b128/slice/wave)
//  3. FSTRB=128 + XOR swizzle; LDS 58.9 -> 53.2 KB -> 3 blocks/CU, (256,3)
__global__ __launch_bounds__(256, 3) void k_main(
    const float* __restrict__ x, const float* __restrict__ Sg,
    const float* __restrict__ U1, const float* __restrict__ w1,
    const int* __restrict__ cnt_g, const int* __restrict__ list_g,
    float* __restrict__ out) {

    __shared__ __align__(16) unsigned short Fh[MROWS * 64];   // 16,384 B
    __shared__ __align__(16) unsigned short Fl[MROWS * 64];   // 16,384 B
    __shared__ __align__(16) unsigned short Sh[48 * 64];      //  6,144 B
    __shared__ __align__(16) unsigned short Sl[48 * 64];      //  6,144 B
    __shared__ __align__(16) float XL[MROWS * ELL];           //  8,192 B
    // total 53,248 B -> 3 blocks/CU

    const int t    = threadIdx.x;
    const int c    = blockIdx.x;
    const int e    = blockIdx.y;
    const int lane = t & 63;
    const int wv   = t >> 6;           // wave 0..3
    const int lr   = lane & 15;        // A-row/B-col/D-col (xx)
    const int lq   = lane >> 4;        // 0..3
    const int frow = t >> 1;           // F-build: own row 0..127
    const int fhalf = t & 1;           // F-build: slot half 0/1
    const int cnt  = cnt_g[e];
    const int cntp = (cnt + 127) & ~127;
    const float w1ec = w1[e * C_ + c];
    const float* sgbase = Sg + (size_t)(e * C_ + c) * SRS;

    for (int base = 0; base < cntp; base += MROWS) {
        if (base > 0) __syncthreads();   // protect XL/F/S vs prev chunk

        // ---- stage X rows (list_g padded x128 -> no guards)
        if (t < MROWS) {
            const int b = list_g[e * B_ + base + t];
            const float* xb = x + ((size_t)b * C_ + c) * ELL;
            float4* dst = (float4*)&XL[t * ELL];
            #pragma unroll
            for (int i4 = 0; i4 < 4; ++i4) dst[i4] = ((const float4*)xb)[i4];
        }
        __syncthreads();

        // own F-row in registers (shared by both halves of the row)
        float xr[16];
        #pragma unroll
        for (int i4 = 0; i4 < 4; ++i4) {
            float4 a = *(const float4*)&XL[frow * ELL + 4 * i4];
            xr[4 * i4 + 0] = a.x; xr[4 * i4 + 1] = a.y;
            xr[4 * i4 + 2] = a.z; xr[4 * i4 + 3] = a.w;
        }

        f32x4 acc[6];
        #pragma unroll
        for (int ti = 0; ti < 6; ++ti) acc[ti] = (f32x4){0.f, 0.f, 0.f, 0.f};

        #pragma unroll
        for (int ks = 0; ks < 3; ++ks) {
            // ---- build F slice (row-owner, compile-time slots)
            if (fhalf == 0) {
                if (ks == 0) build_F<0, 0>(xr, frow, Fh, Fl);
                if (ks == 1) build_F<1, 0>(xr, frow, Fh, Fl);
                if (ks == 2) build_F<2, 0>(xr, frow, Fh, Fl);
            } else {
                if (ks == 0) build_F<0, 1>(xr, frow, Fh, Fl);
                if (ks == 1) build_F<1, 1>(xr, frow, Fh, Fl);
                if (ks == 2) build_F<2, 1>(xr, frow, Fh, Fl);
            }
            // ---- build S slice: threads 0..191, n = t>>2, 16 k's each
            if (t < 192) {
                const int n = t >> 2, q = t & 3;
                #pragma unroll
                for (int g = 0; g < 2; ++g) {
                    short8 hi, lo;
                    #pragma unroll
                    for (int j8 = 0; j8 < 8; ++j8) {
                        const int kl = q * 16 + g * 8 + j8;
                        const int slot2 = ks * KSL + kl;
                        const float sv = (slot2 < NSEG)
                                       ? sgbase[n * RSTR + slot2] : 0.f;
                        const unsigned short h = bf16_rne(sv);
                        hi[j8] = (short)h;
                        lo[j8] = (short)bf16_rne(sv - bf16_to_f(h));
                    }
                    const int off = SWZ(n, (q * 16 + g * 8) * 2);
                    *(short8*)((char*)Sh + n * FSTRB + off) = hi;
                    *(short8*)((char*)Sl + n * FSTRB + off) = lo;
                }
            }
            __syncthreads();

            // ---- GEMM: wave wv owns m in {2wv, 2wv+1}, n in {0,1,2}
            #pragma unroll
            for (int kst = 0; kst < 2; ++kst) {
                const int ko = kst * 64 + lq * 16;   // byte offset in k
                short8 ah[2], al[2];
                #pragma unroll
                for (int m2 = 0; m2 < 2; ++m2) {
                    const int row = (2 * wv + m2) * 16 + lr;
                    const int off = SWZ(row, ko);
                    ah[m2] = *(const short8*)((const char*)Fh + row * FSTRB + off);
                    al[m2] = *(const short8*)((const char*)Fl + row * FSTRB + off);
                }
                #pragma unroll
                for (int n = 0; n < 3; ++n) {
                    const int col = n * 16 + lr;
                    const int off = SWZ(col, ko);
                    short8 bh = *(const short8*)((const char*)Sh + col * FSTRB + off);
                    short8 bl = *(const short8*)((const char*)Sl + col * FSTRB + off);
                    #pragma unroll
                    for (int m2 = 0; m2 < 2; ++m2) {
                        acc[m2 * 3 + n] = __builtin_amdgcn_mfma_f32_16x16x32_bf16(
                                              ah[m2], bh, acc[m2 * 3 + n], 0, 0, 0);
                        acc[m2 * 3 + n] = __builtin_amdgcn_mfma_f32_16x16x32_bf16(
                                              ah[m2], bl, acc[m2 * 3 + n], 0, 0, 0);
                        acc[m2 * 3 + n] = __builtin_amdgcn_mfma_f32_16x16x32_bf16(
                                              al[m2], bh, acc[m2 * 3 + n], 0, 0, 0);
                    }
                }
            }
            if (ks < 2) __syncthreads();   // GEMM done before next build
        }

        // ---- epilogue: xx-contraction via verified DPP tree
        #pragma unroll
        for (int m2 = 0; m2 < 2; ++m2) {
            #pragma unroll
            for (int n = 0; n < 3; ++n) {
                const float v1x = U1[n * 16 + lr] * w1ec;
                #pragma unroll
                for (int reg = 0; reg < 4; ++reg) {
                    const int row = (2 * wv + m2) * 16 + lq * 4 + reg;
                    const float xmv = XL[row * ELL + lr];
                    float cv = (acc[m2 * 3 + n][reg] + v1x) * xmv;
                    cv = row16_sum(cv);
                    if (lr == 0) {
                        const int gslot = base + row;
                        if (gslot < cnt) {
                            const int b = list_g[e * B_ + gslot];
                            out[(size_t)b * (C_ * EQ) + c * EQ + n] = cv;
                        }
                    }
                }
            }
        }
    }
}

// ---------------------------------------------------------------------------
extern "C" void kernel_launch(void* const* d_in, const int* in_sizes, int n_in,
                              void* d_out, int out_size, void* d_ws, size_t ws_size,
                              hipStream_t stream) {
    const float* x    = (const float*)d_in[0];
    const float* y    = (const float*)d_in[1];
    const float* U3   = (const float*)d_in[2];
    const float* U2   = (const float*)d_in[3];
    const float* U1   = (const float*)d_in[4];
    const float* wmax = (const float*)d_in[5];
    const float* w2   = (const float*)d_in[6];
    const float* w1   = (const float*)d_in[7];
    float* out = (float*)d_out;
    char*  ws  = (char*)d_ws;

    int*   cnt_g  = (int*)(ws + 0);
    int*   list_g = (int*)(ws + 64);
    float* Sg     = (float*)(ws + 65536);
    (void)ws_size;   // 44.3 MB needed; harness ws confirmed >= 66 MB

    k_s<<<dim3(49, E_, 4), 256, 0, stream>>>(U3, U2, wmax, w2, y, Sg, cnt_g, list_g);
    k_main<<<dim3(C_, E_), 256, 0, stream>>>(x, Sg, U1, w1, cnt_g, list_g, out);
}

// Round 17
// 120.946 us; speedup vs baseline: 1.4330x; 1.0174x over previous
//
#include <hip/hip_runtime.h>

// Problem constants
#define B_    1024
#define C_    128
#define ELL   16
#define EQ    3
#define E_    10
#define P3    23
#define P2    5
#define NSEG  176            // real segment slots; K padded to 192
#define RSTR  180            // Sg row stride (floats)
#define SRS   (48 * RSTR)    // 8640 floats per (e,c) S-slice
#define KD    28             // folded weight depth: 23 (wmax) + 5 (w2)

// MFMA geometry (k_main r27/r28)
#define MROWS 128            // padded bucket rows per chunk
#define KSL   64             // K-slice width; 3 slices cover 192
#define FSTRB 128            // bf16 row stride in BYTES (64 shorts, pow2 + swizzle)
// XOR swizzle (guide G4): spreads pow2 row stride across 8 LDS spans.
#define SWZ(row, byteoff) ((byteoff) ^ (((row) & 7) << 4))

typedef float v2f __attribute__((ext_vector_type(2)));
using short8 = __attribute__((ext_vector_type(8))) short;   // 8 bf16
using f32x4  = __attribute__((ext_vector_type(4))) float;   // MFMA C/D

#define SEG_OFF_INIT {0,20,36,52,68,84,96,108,120,132,140,148,156,164,168,172}

// ---------------------------------------------------------------------------
// bf16 split via NATIVE conversion (r28): (__bf16) cast is RNE and the
// compiler pairs casts into v_cvt_pk_bf16_f32 (guide m240: scalar cast is
// the fast path; hand-written cvt_pk asm was -37%). Replaces the soft-RNE
// routine (~12 int ops/element -> ~4): F-build 96 + S-build 32 elements per
// thread per chunk ~= 1000 VALU ops saved. Numerics identical (both RNE) --
// absmax must stay 0.03125 (tripwire if not).
__device__ __forceinline__ unsigned short f2bf(float f) {
    union { __bf16 h; unsigned short u; } cv;
    cv.h = (__bf16)f;
    return cv.u;
}
__device__ __forceinline__ float bf2f(unsigned short u) {
    return __uint_as_float(((unsigned int)u) << 16);
}
__device__ __forceinline__ void split_bf16(float f, short &hi, short &lo) {
    const unsigned short h = f2bf(f);
    hi = (short)h;
    lo = (short)f2bf(f - bf2f(h));
}

// DPP row_ror width-16 sum-to-all. VERIFIED r18b-r27.
template <int CTRL>
__device__ __forceinline__ float dpp_ror_add(float v) {
    int s = __float_as_int(v);
    int r = __builtin_amdgcn_update_dpp(s, s, CTRL, 0xF, 0xF, false);
    return v + __int_as_float(r);
}
__device__ __forceinline__ float row16_sum(float v) {
    v = dpp_ror_add<0x121>(v);
    v = dpp_ror_add<0x122>(v);
    v = dpp_ror_add<0x124>(v);
    v = dpp_ror_add<0x128>(v);
    return v;
}

// ---------------------------------------------------------------------------
// Bucketing: pad to x128 (r18b/r26/r27-verified).
__device__ void do_lists(const float* __restrict__ y, int* __restrict__ cnt_g,
                         int* __restrict__ list_g, int t) {
    __shared__ int lcnt[E_];
    if (t < E_) lcnt[t] = 0;
    __syncthreads();
    for (int r = 0; r < 4; ++r) {
        int b = t + 256 * r;
        int e = 0;
        #pragma unroll
        for (int j = 1; j < E_; ++j)
            if (y[b * E_ + j] > 0.5f) e = j;
        int slot = atomicAdd(&lcnt[e], 1);
        list_g[e * B_ + slot] = b;
    }
    __syncthreads();
    if (t < E_) {
        int c0 = lcnt[t];
        cnt_g[t] = c0;
        int last = (c0 > 0) ? list_g[t * B_ + c0 - 1] : 0;
        int cp = (c0 + 127) & ~127;
        if (cp > B_) cp = B_;
        for (int s2 = c0; s2 < cp; ++s2) list_g[t * B_ + s2] = last;
    }
}

// ---------------------------------------------------------------------------
// k_s = EXACT r17 (verified win). Unchanged.
__global__ __launch_bounds__(256, 2) void k_s(const float* __restrict__ U3,
                                              const float* __restrict__ U2,
                                              const float* __restrict__ wmax,
                                              const float* __restrict__ w2,
                                              const float* __restrict__ y,
                                              float* __restrict__ Sg,
                                              int* __restrict__ cnt_g,
                                              int* __restrict__ list_g) {
    const int t = threadIdx.x;
    if (blockIdx.x == 48) {
        if (blockIdx.y == 0 && blockIdx.z == 0) do_lists(y, cnt_g, list_g, t);
        return;
    }
    __shared__ __align__(16) float wsm[KD * 32];
    __shared__ __align__(16) float SKL[NSEG * KD];

    const int j  = blockIdx.x;
    const int e  = blockIdx.y;
    const int cq = blockIdx.z;

    for (int idx = t; idx < KD * 32; idx += 256) {
        int k = idx >> 5, cc = idx & 31, c = cq * 32 + cc;
        wsm[idx] = (k < 23) ? wmax[(e * P3 + k) * C_ + c]
                            : w2[(e * P2 + (k - 23)) * C_ + c];
    }

    if (t < NSEG) {
        const int SO[16] = SEG_OFF_INIT;
        int v = 0;
        #pragma unroll
        for (int s = 1; s < 16; ++s) v += (t >= SO[s]) ? 1 : 0;
        const int l    = t - SO[v];
        const int real = 17 - v;

        float row[KD];
        #pragma unroll
        for (int d = 0; d < KD; ++d) row[d] = 0.f;

        if (l == 0) {
            #pragma unroll
            for (int q = 0; q < P2; ++q)
                row[23 + q] = U2[(size_t)j * (ELL * P2) + v * P2 + q];
        } else if (l < real) {
            int i = v + l - 1;
            const float* pa = U3 + (size_t)j * (ELL * ELL * P3) + (v * ELL + i) * P3;
            const float* pb = U3 + (size_t)j * (ELL * ELL * P3) + (i * ELL + v) * P3;
            if (i != v) {
                #pragma unroll
                for (int k = 0; k < P3; ++k) row[k] = pa[k] + pb[k];
            } else {
                #pragma unroll
                for (int k = 0; k < P3; ++k) row[k] = pa[k];
            }
        }

        float* dst = &SKL[t * KD];
        #pragma unroll
        for (int d4 = 0; d4 < KD / 4; ++d4)
            *(float4*)(dst + 4 * d4) = make_float4(row[4 * d4], row[4 * d4 + 1],
                                                   row[4 * d4 + 2], row[4 * d4 + 3]);
    }
    __syncthreads();

    if (t >= NSEG) return;

    const int sg = t % 44;
    const int cg = t / 44;
    const int c8 = cg * 8;

    v2f acc[4][4];
    #pragma unroll
    for (int s = 0; s < 4; ++s)
        #pragma unroll
        for (int cp2 = 0; cp2 < 4; ++cp2) acc[s][cp2] = (v2f){0.f, 0.f};

    #pragma unroll
    for (int k4 = 0; k4 < KD / 4; ++k4) {
        float4 sk4[4];
        #pragma unroll
        for (int s = 0; s < 4; ++s)
            sk4[s] = *(const float4*)&SKL[(sg + 44 * s) * KD + 4 * k4];
        #pragma unroll
        for (int kk = 0; kk < 4; ++kk) {
            const int k = 4 * k4 + kk;
            float4 w0 = *(const float4*)&wsm[k * 32 + c8];
            float4 w1 = *(const float4*)&wsm[k * 32 + c8 + 4];
            v2f wp0 = {w0.x, w0.y}, wp1 = {w0.z, w0.w};
            v2f wp2 = {w1.x, w1.y}, wp3 = {w1.z, w1.w};
            #pragma unroll
            for (int s = 0; s < 4; ++s) {
                const float skv = (kk == 0) ? sk4[s].x : (kk == 1) ? sk4[s].y
                                : (kk == 2) ? sk4[s].z : sk4[s].w;
                acc[s][0] += skv * wp0;
                acc[s][1] += skv * wp1;
                acc[s][2] += skv * wp2;
                acc[s][3] += skv * wp3;
            }
        }
    }

    #pragma unroll
    for (int s = 0; s < 4; ++s) {
        const int slot = sg + 44 * s;
        #pragma unroll
        for (int cc = 0; cc < 8; ++cc) {
            const int c = cq * 32 + c8 + cc;
            Sg[(size_t)(e * C_ + c) * SRS + j * RSTR + slot] = acc[s][cc >> 1][cc & 1];
        }
    }
}

// ---------------------------------------------------------------------------
// build_F<KS,HALF>: this thread's row, 32 compile-time slots -> packed b128.
// r28: split_bf16 now uses native cvt (was soft RNE).
template <int KS, int HALF>
__device__ __forceinline__ void build_F(const float (&xr)[16], int row,
                                        unsigned short* __restrict__ Fh,
                                        unsigned short* __restrict__ Fl) {
    const int SO[16] = SEG_OFF_INIT;
    #pragma unroll
    for (int g = 0; g < 4; ++g) {
        short8 hi, lo;
        #pragma unroll
        for (int j8 = 0; j8 < 8; ++j8) {
            const int slot = KS * KSL + HALF * 32 + g * 8 + j8;   // CT
            int v = 0;
            #pragma unroll
            for (int s = 1; s < 16; ++s) v += (slot >= SO[s]) ? 1 : 0;
            const int l    = slot - SO[v];
            const int real = 17 - v;
            const bool is_lin = (slot < NSEG) && (l == 0);
            const bool is_q   = (slot < NSEG) && (l > 0) && (l < real);
            const int  iq     = is_q ? (v + l - 1) : 0;
            const float f = is_lin ? xr[v] : (is_q ? xr[v] * xr[iq] : 0.f);
            short h, lw;
            split_bf16(f, h, lw);
            hi[j8] = h;
            lo[j8] = lw;
        }
        const int off = SWZ(row, HALF * 64 + g * 16);
        *(short8*)((char*)Fh + row * FSTRB + off) = hi;
        *(short8*)((char*)Fl + row * FSTRB + off) = lo;
    }
}

// ---------------------------------------------------------------------------
// k_main r28 = r27 (verified pass, ~37us inferred) + native bf16 cvt.
// r27 post-mortem: k_main fell below the harness fill kernels (~43.5us) --
// the three r26-PMC fixes (F-build b128, 2mx3n retile, swizzle+53KB LDS)
// worked. Remaining VALU load is dominated by the soft-RNE conversions;
// this round swaps them for native casts (m240: scalar cast = fast path).
__global__ __launch_bounds__(256, 3) void k_main(
    const float* __restrict__ x, const float* __restrict__ Sg,
    const float* __restrict__ U1, const float* __restrict__ w1,
    const int* __restrict__ cnt_g, const int* __restrict__ list_g,
    float* __restrict__ out) {

    __shared__ __align__(16) unsigned short Fh[MROWS * 64];   // 16,384 B
    __shared__ __align__(16) unsigned short Fl[MROWS * 64];   // 16,384 B
    __shared__ __align__(16) unsigned short Sh[48 * 64];      //  6,144 B
    __shared__ __align__(16) unsigned short Sl[48 * 64];      //  6,144 B
    __shared__ __align__(16) float XL[MROWS * ELL];           //  8,192 B
    // total 53,248 B -> 3 blocks/CU

    const int t    = threadIdx.x;
    const int c    = blockIdx.x;
    const int e    = blockIdx.y;
    const int lane = t & 63;
    const int wv   = t >> 6;           // wave 0..3
    const int lr   = lane & 15;        // A-row/B-col/D-col (xx)
    const int lq   = lane >> 4;        // 0..3
    const int frow = t >> 1;           // F-build: own row 0..127
    const int fhalf = t & 1;           // F-build: slot half 0/1
    const int cnt  = cnt_g[e];
    const int cntp = (cnt + 127) & ~127;
    const float w1ec = w1[e * C_ + c];
    const float* sgbase = Sg + (size_t)(e * C_ + c) * SRS;

    for (int base = 0; base < cntp; base += MROWS) {
        if (base > 0) __syncthreads();   // protect XL/F/S vs prev chunk

        // ---- stage X rows (list_g padded x128 -> no guards)
        if (t < MROWS) {
            const int b = list_g[e * B_ + base + t];
            const float* xb = x + ((size_t)b * C_ + c) * ELL;
            float4* dst = (float4*)&XL[t * ELL];
            #pragma unroll
            for (int i4 = 0; i4 < 4; ++i4) dst[i4] = ((const float4*)xb)[i4];
        }
        __syncthreads();

        // own F-row in registers (shared by both halves of the row)
        float xr[16];
        #pragma unroll
        for (int i4 = 0; i4 < 4; ++i4) {
            float4 a = *(const float4*)&XL[frow * ELL + 4 * i4];
            xr[4 * i4 + 0] = a.x; xr[4 * i4 + 1] = a.y;
            xr[4 * i4 + 2] = a.z; xr[4 * i4 + 3] = a.w;
        }

        f32x4 acc[6];
        #pragma unroll
        for (int ti = 0; ti < 6; ++ti) acc[ti] = (f32x4){0.f, 0.f, 0.f, 0.f};

        #pragma unroll
        for (int ks = 0; ks < 3; ++ks) {
            // ---- build F slice (row-owner, compile-time slots)
            if (fhalf == 0) {
                if (ks == 0) build_F<0, 0>(xr, frow, Fh, Fl);
                if (ks == 1) build_F<1, 0>(xr, frow, Fh, Fl);
                if (ks == 2) build_F<2, 0>(xr, frow, Fh, Fl);
            } else {
                if (ks == 0) build_F<0, 1>(xr, frow, Fh, Fl);
                if (ks == 1) build_F<1, 1>(xr, frow, Fh, Fl);
                if (ks == 2) build_F<2, 1>(xr, frow, Fh, Fl);
            }
            // ---- build S slice: threads 0..191, n = t>>2, 16 k's each
            if (t < 192) {
                const int n = t >> 2, q = t & 3;
                #pragma unroll
                for (int g = 0; g < 2; ++g) {
                    short8 hi, lo;
                    #pragma unroll
                    for (int j8 = 0; j8 < 8; ++j8) {
                        const int kl = q * 16 + g * 8 + j8;
                        const int slot2 = ks * KSL + kl;
                        const float sv = (slot2 < NSEG)
                                       ? sgbase[n * RSTR + slot2] : 0.f;
                        short h, lw;
                        split_bf16(sv, h, lw);
                        hi[j8] = h;
                        lo[j8] = lw;
                    }
                    const int off = SWZ(n, (q * 16 + g * 8) * 2);
                    *(short8*)((char*)Sh + n * FSTRB + off) = hi;
                    *(short8*)((char*)Sl + n * FSTRB + off) = lo;
                }
            }
            __syncthreads();

            // ---- GEMM: wave wv owns m in {2wv, 2wv+1}, n in {0,1,2}
            #pragma unroll
            for (int kst = 0; kst < 2; ++kst) {
                const int ko = kst * 64 + lq * 16;   // byte offset in k
                short8 ah[2], al[2];
                #pragma unroll
                for (int m2 = 0; m2 < 2; ++m2) {
                    const int row = (2 * wv + m2) * 16 + lr;
                    const int off = SWZ(row, ko);
                    ah[m2] = *(const short8*)((const char*)Fh + row * FSTRB + off);
                    al[m2] = *(const short8*)((const char*)Fl + row * FSTRB + off);
                }
                #pragma unroll
                for (int n = 0; n < 3; ++n) {
                    const int col = n * 16 + lr;
                    const int off = SWZ(col, ko);
                    short8 bh = *(const short8*)((const char*)Sh + col * FSTRB + off);
                    short8 bl = *(const short8*)((const char*)Sl + col * FSTRB + off);
                    #pragma unroll
                    for (int m2 = 0; m2 < 2; ++m2) {
                        acc[m2 * 3 + n] = __builtin_amdgcn_mfma_f32_16x16x32_bf16(
                                              ah[m2], bh, acc[m2 * 3 + n], 0, 0, 0);
                        acc[m2 * 3 + n] = __builtin_amdgcn_mfma_f32_16x16x32_bf16(
                                              ah[m2], bl, acc[m2 * 3 + n], 0, 0, 0);
                        acc[m2 * 3 + n] = __builtin_amdgcn_mfma_f32_16x16x32_bf16(
                                              al[m2], bh, acc[m2 * 3 + n], 0, 0, 0);
                    }
                }
            }
            if (ks < 2) __syncthreads();   // GEMM done before next build
        }

        // ---- epilogue: xx-contraction via verified DPP tree
        #pragma unroll
        for (int m2 = 0; m2 < 2; ++m2) {
            #pragma unroll
            for (int n = 0; n < 3; ++n) {
                const float v1x = U1[n * 16 + lr] * w1ec;
                #pragma unroll
                for (int reg = 0; reg < 4; ++reg) {
                    const int row = (2 * wv + m2) * 16 + lq * 4 + reg;
                    const float xmv = XL[row * ELL + lr];
                    float cv = (acc[m2 * 3 + n][reg] + v1x) * xmv;
                    cv = row16_sum(cv);
                    if (lr == 0) {
                        const int gslot = base + row;
                        if (gslot < cnt) {
                            const int b = list_g[e * B_ + gslot];
                            out[(size_t)b * (C_ * EQ) + c * EQ + n] = cv;
                        }
                    }
                }
            }
        }
    }
}

// ---------------------------------------------------------------------------
extern "C" void kernel_launch(void* const* d_in, const int* in_sizes, int n_in,
                              void* d_out, int out_size, void* d_ws, size_t ws_size,
                              hipStream_t stream) {
    const float* x    = (const float*)d_in[0];
    const float* y    = (const float*)d_in[1];
    const float* U3   = (const float*)d_in[2];
    const float* U2   = (const float*)d_in[3];
    const float* U1   = (const float*)d_in[4];
    const float* wmax = (const float*)d_in[5];
    const float* w2   = (const float*)d_in[6];
    const float* w1   = (const float*)d_in[7];
    float* out = (float*)d_out;
    char*  ws  = (char*)d_ws;

    int*   cnt_g  = (int*)(ws + 0);
    int*   list_g = (int*)(ws + 64);
    float* Sg     = (float*)(ws + 65536);
    (void)ws_size;   // 44.3 MB needed; harness ws confirmed >= 66 MB

    k_s<<<dim3(49, E_, 4), 256, 0, stream>>>(U3, U2, wmax, w2, y, Sg, cnt_g, list_g);
    k_main<<<dim3(C_, E_), 256, 0, stream>>>(x, Sg, U1, w1, cnt_g, list_g, out);
}

// Round 18
// 119.716 us; speedup vs baseline: 1.4477x; 1.0103x over previous
//
#include <hip/hip_runtime.h>

// Problem constants
#define B_    1024
#define C_    128
#define ELL   16
#define EQ    3
#define E_    10
#define P3    23
#define P2    5
#define NSEG  176            // real segment slots; K padded to 192
#define RSTR  180            // Sg row stride (floats)
#define SRS   (48 * RSTR)    // 8640 floats per (e,c) S-slice
#define KD    28             // folded weight depth: 23 (wmax) + 5 (w2)

// MFMA geometry (k_main r29): KSL 64->32, 6 slices. Same instruction totals
// as r28; LDS 53.2KB -> 30.7KB raises residency 3 -> 4(+1 queued) blocks/CU.
#define MROWS 128            // padded bucket rows per chunk
#define KSL   32             // K-slice width; 6 slices cover 192
#define NSLICE 6
#define FSTRB 64             // bf16 row stride in BYTES (32 shorts)
// XOR swizzle for 64B rows: 4 16B-groups, XOR group idx with row&3.
// GEMM read (16 rows, fixed ko): spans = (r*4 + (g ^ (r&3))) % 8 -> 8
// distinct spans x 2 lanes = 2-way (free, m136). Without: 8-way (2.94x).
#define SWZ(row, byteoff) ((byteoff) ^ (((row) & 3) << 4))

typedef float v2f __attribute__((ext_vector_type(2)));
using short8 = __attribute__((ext_vector_type(8))) short;   // 8 bf16
using f32x4  = __attribute__((ext_vector_type(4))) float;   // MFMA C/D

#define SEG_OFF_INIT {0,20,36,52,68,84,96,108,120,132,140,148,156,164,168,172}

// ---------------------------------------------------------------------------
// bf16 split via NATIVE conversion (r28-verified: absmax 0.03125 identical).
__device__ __forceinline__ unsigned short f2bf(float f) {
    union { __bf16 h; unsigned short u; } cv;
    cv.h = (__bf16)f;
    return cv.u;
}
__device__ __forceinline__ float bf2f(unsigned short u) {
    return __uint_as_float(((unsigned int)u) << 16);
}
__device__ __forceinline__ void split_bf16(float f, short &hi, short &lo) {
    const unsigned short h = f2bf(f);
    hi = (short)h;
    lo = (short)f2bf(f - bf2f(h));
}

// DPP row_ror width-16 sum-to-all. VERIFIED r18b-r28.
template <int CTRL>
__device__ __forceinline__ float dpp_ror_add(float v) {
    int s = __float_as_int(v);
    int r = __builtin_amdgcn_update_dpp(s, s, CTRL, 0xF, 0xF, false);
    return v + __int_as_float(r);
}
__device__ __forceinline__ float row16_sum(float v) {
    v = dpp_ror_add<0x121>(v);
    v = dpp_ror_add<0x122>(v);
    v = dpp_ror_add<0x124>(v);
    v = dpp_ror_add<0x128>(v);
    return v;
}

// ---------------------------------------------------------------------------
// Bucketing: pad to x128 (r18b/r26-r28-verified).
__device__ void do_lists(const float* __restrict__ y, int* __restrict__ cnt_g,
                         int* __restrict__ list_g, int t) {
    __shared__ int lcnt[E_];
    if (t < E_) lcnt[t] = 0;
    __syncthreads();
    for (int r = 0; r < 4; ++r) {
        int b = t + 256 * r;
        int e = 0;
        #pragma unroll
        for (int j = 1; j < E_; ++j)
            if (y[b * E_ + j] > 0.5f) e = j;
        int slot = atomicAdd(&lcnt[e], 1);
        list_g[e * B_ + slot] = b;
    }
    __syncthreads();
    if (t < E_) {
        int c0 = lcnt[t];
        cnt_g[t] = c0;
        int last = (c0 > 0) ? list_g[t * B_ + c0 - 1] : 0;
        int cp = (c0 + 127) & ~127;
        if (cp > B_) cp = B_;
        for (int s2 = c0; s2 < cp; ++s2) list_g[t * B_ + s2] = last;
    }
}

// ---------------------------------------------------------------------------
// k_s = EXACT r17 (verified win). Unchanged.
__global__ __launch_bounds__(256, 2) void k_s(const float* __restrict__ U3,
                                              const float* __restrict__ U2,
                                              const float* __restrict__ wmax,
                                              const float* __restrict__ w2,
                                              const float* __restrict__ y,
                                              float* __restrict__ Sg,
                                              int* __restrict__ cnt_g,
                                              int* __restrict__ list_g) {
    const int t = threadIdx.x;
    if (blockIdx.x == 48) {
        if (blockIdx.y == 0 && blockIdx.z == 0) do_lists(y, cnt_g, list_g, t);
        return;
    }
    __shared__ __align__(16) float wsm[KD * 32];
    __shared__ __align__(16) float SKL[NSEG * KD];

    const int j  = blockIdx.x;
    const int e  = blockIdx.y;
    const int cq = blockIdx.z;

    for (int idx = t; idx < KD * 32; idx += 256) {
        int k = idx >> 5, cc = idx & 31, c = cq * 32 + cc;
        wsm[idx] = (k < 23) ? wmax[(e * P3 + k) * C_ + c]
                            : w2[(e * P2 + (k - 23)) * C_ + c];
    }

    if (t < NSEG) {
        const int SO[16] = SEG_OFF_INIT;
        int v = 0;
        #pragma unroll
        for (int s = 1; s < 16; ++s) v += (t >= SO[s]) ? 1 : 0;
        const int l    = t - SO[v];
        const int real = 17 - v;

        float row[KD];
        #pragma unroll
        for (int d = 0; d < KD; ++d) row[d] = 0.f;

        if (l == 0) {
            #pragma unroll
            for (int q = 0; q < P2; ++q)
                row[23 + q] = U2[(size_t)j * (ELL * P2) + v * P2 + q];
        } else if (l < real) {
            int i = v + l - 1;
            const float* pa = U3 + (size_t)j * (ELL * ELL * P3) + (v * ELL + i) * P3;
            const float* pb = U3 + (size_t)j * (ELL * ELL * P3) + (i * ELL + v) * P3;
            if (i != v) {
                #pragma unroll
                for (int k = 0; k < P3; ++k) row[k] = pa[k] + pb[k];
            } else {
                #pragma unroll
                for (int k = 0; k < P3; ++k) row[k] = pa[k];
            }
        }

        float* dst = &SKL[t * KD];
        #pragma unroll
        for (int d4 = 0; d4 < KD / 4; ++d4)
            *(float4*)(dst + 4 * d4) = make_float4(row[4 * d4], row[4 * d4 + 1],
                                                   row[4 * d4 + 2], row[4 * d4 + 3]);
    }
    __syncthreads();

    if (t >= NSEG) return;

    const int sg = t % 44;
    const int cg = t / 44;
    const int c8 = cg * 8;

    v2f acc[4][4];
    #pragma unroll
    for (int s = 0; s < 4; ++s)
        #pragma unroll
        for (int cp2 = 0; cp2 < 4; ++cp2) acc[s][cp2] = (v2f){0.f, 0.f};

    #pragma unroll
    for (int k4 = 0; k4 < KD / 4; ++k4) {
        float4 sk4[4];
        #pragma unroll
        for (int s = 0; s < 4; ++s)
            sk4[s] = *(const float4*)&SKL[(sg + 44 * s) * KD + 4 * k4];
        #pragma unroll
        for (int kk = 0; kk < 4; ++kk) {
            const int k = 4 * k4 + kk;
            float4 w0 = *(const float4*)&wsm[k * 32 + c8];
            float4 w1 = *(const float4*)&wsm[k * 32 + c8 + 4];
            v2f wp0 = {w0.x, w0.y}, wp1 = {w0.z, w0.w};
            v2f wp2 = {w1.x, w1.y}, wp3 = {w1.z, w1.w};
            #pragma unroll
            for (int s = 0; s < 4; ++s) {
                const float skv = (kk == 0) ? sk4[s].x : (kk == 1) ? sk4[s].y
                                : (kk == 2) ? sk4[s].z : sk4[s].w;
                acc[s][0] += skv * wp0;
                acc[s][1] += skv * wp1;
                acc[s][2] += skv * wp2;
                acc[s][3] += skv * wp3;
            }
        }
    }

    #pragma unroll
    for (int s = 0; s < 4; ++s) {
        const int slot = sg + 44 * s;
        #pragma unroll
        for (int cc = 0; cc < 8; ++cc) {
            const int c = cq * 32 + c8 + cc;
            Sg[(size_t)(e * C_ + c) * SRS + j * RSTR + slot] = acc[s][cc >> 1][cc & 1];
        }
    }
}

// ---------------------------------------------------------------------------
// build_F<KS,HALF>: this thread's row, 16 compile-time slots -> packed b128.
// (KSL=32: each half covers 16 slots = 2 groups of 8.)
template <int KS, int HALF>
__device__ __forceinline__ void build_F(const float (&xr)[16], int row,
                                        unsigned short* __restrict__ Fh,
                                        unsigned short* __restrict__ Fl) {
    const int SO[16] = SEG_OFF_INIT;
    #pragma unroll
    for (int g = 0; g < 2; ++g) {
        short8 hi, lo;
        #pragma unroll
        for (int j8 = 0; j8 < 8; ++j8) {
            const int slot = KS * KSL + HALF * 16 + g * 8 + j8;   // CT
            int v = 0;
            #pragma unroll
            for (int s = 1; s < 16; ++s) v += (slot >= SO[s]) ? 1 : 0;
            const int l    = slot - SO[v];
            const int real = 17 - v;
            const bool is_lin = (slot < NSEG) && (l == 0);
            const bool is_q   = (slot < NSEG) && (l > 0) && (l < real);
            const int  iq     = is_q ? (v + l - 1) : 0;
            const float f = is_lin ? xr[v] : (is_q ? xr[v] * xr[iq] : 0.f);
            short h, lw;
            split_bf16(f, h, lw);
            hi[j8] = h;
            lo[j8] = lw;
        }
        const int off = SWZ(row, HALF * 32 + g * 16);
        *(short8*)((char*)Fh + row * FSTRB + off) = hi;
        *(short8*)((char*)Fl + row * FSTRB + off) = lo;
    }
}

// ---------------------------------------------------------------------------
// k_main r29 = r28 math (verified, absmax 0.03125) re-sliced KSL 64->32.
// r28 post-mortem: issue model says ~9-12us, inferred ~35us -> k_main is
// BARRIER-bound at 3 blocks/CU residency (53.2KB LDS), not issue-bound.
// KSL=32: identical MFMA (108), identical b128 reads (60/wave), identical
// conversion counts; LDS 30.7KB -> 4 blocks/CU resident (5th queued),
// barriers 7 -> 13 per chunk. Direct test of the residency theory.
__global__ __launch_bounds__(256, 4) void k_main(
    const float* __restrict__ x, const float* __restrict__ Sg,
    const float* __restrict__ U1, const float* __restrict__ w1,
    const int* __restrict__ cnt_g, const int* __restrict__ list_g,
    float* __restrict__ out) {

    __shared__ __align__(16) unsigned short Fh[MROWS * KSL];  // 8,192 B
    __shared__ __align__(16) unsigned short Fl[MROWS * KSL];  // 8,192 B
    __shared__ __align__(16) unsigned short Sh[48 * KSL];     // 3,072 B
    __shared__ __align__(16) unsigned short Sl[48 * KSL];     // 3,072 B
    __shared__ __align__(16) float XL[MROWS * ELL];           // 8,192 B
    // total 30,720 B -> LDS allows 5 blocks/CU; (256,4) VGPR cap -> 4

    const int t    = threadIdx.x;
    const int c    = blockIdx.x;
    const int e    = blockIdx.y;
    const int lane = t & 63;
    const int wv   = t >> 6;           // wave 0..3
    const int lr   = lane & 15;        // A-row/B-col/D-col (xx)
    const int lq   = lane >> 4;        // 0..3
    const int frow = t >> 1;           // F-build: own row 0..127
    const int fhalf = t & 1;           // F-build: slot half 0/1
    const int cnt  = cnt_g[e];
    const int cntp = (cnt + 127) & ~127;
    const float w1ec = w1[e * C_ + c];
    const float* sgbase = Sg + (size_t)(e * C_ + c) * SRS;

    for (int base = 0; base < cntp; base += MROWS) {
        if (base > 0) __syncthreads();   // protect XL/F/S vs prev chunk

        // ---- stage X rows (list_g padded x128 -> no guards)
        if (t < MROWS) {
            const int b = list_g[e * B_ + base + t];
            const float* xb = x + ((size_t)b * C_ + c) * ELL;
            float4* dst = (float4*)&XL[t * ELL];
            #pragma unroll
            for (int i4 = 0; i4 < 4; ++i4) dst[i4] = ((const float4*)xb)[i4];
        }
        __syncthreads();

        // own F-row in registers (shared by both halves of the row)
        float xr[16];
        #pragma unroll
        for (int i4 = 0; i4 < 4; ++i4) {
            float4 a = *(const float4*)&XL[frow * ELL + 4 * i4];
            xr[4 * i4 + 0] = a.x; xr[4 * i4 + 1] = a.y;
            xr[4 * i4 + 2] = a.z; xr[4 * i4 + 3] = a.w;
        }

        f32x4 acc[6];
        #pragma unroll
        for (int ti = 0; ti < 6; ++ti) acc[ti] = (f32x4){0.f, 0.f, 0.f, 0.f};

        #pragma unroll
        for (int ks = 0; ks < NSLICE; ++ks) {
            // ---- build F slice (row-owner, compile-time slots)
            if (fhalf == 0) {
                if (ks == 0) build_F<0, 0>(xr, frow, Fh, Fl);
                if (ks == 1) build_F<1, 0>(xr, frow, Fh, Fl);
                if (ks == 2) build_F<2, 0>(xr, frow, Fh, Fl);
                if (ks == 3) build_F<3, 0>(xr, frow, Fh, Fl);
                if (ks == 4) build_F<4, 0>(xr, frow, Fh, Fl);
                if (ks == 5) build_F<5, 0>(xr, frow, Fh, Fl);
            } else {
                if (ks == 0) build_F<0, 1>(xr, frow, Fh, Fl);
                if (ks == 1) build_F<1, 1>(xr, frow, Fh, Fl);
                if (ks == 2) build_F<2, 1>(xr, frow, Fh, Fl);
                if (ks == 3) build_F<3, 1>(xr, frow, Fh, Fl);
                if (ks == 4) build_F<4, 1>(xr, frow, Fh, Fl);
                if (ks == 5) build_F<5, 1>(xr, frow, Fh, Fl);
            }
            // ---- build S slice: threads 0..95: n = t>>1, half = t&1,
            //      16 k's each (2 groups of 8)
            if (t < 96) {
                const int n = t >> 1, sh2 = t & 1;
                #pragma unroll
                for (int g = 0; g < 2; ++g) {
                    short8 hi, lo;
                    #pragma unroll
                    for (int j8 = 0; j8 < 8; ++j8) {
                        const int kl = sh2 * 16 + g * 8 + j8;
                        const int slot2 = ks * KSL + kl;
                        const float sv = (slot2 < NSEG)
                                       ? sgbase[n * RSTR + slot2] : 0.f;
                        short h, lw;
                        split_bf16(sv, h, lw);
                        hi[j8] = h;
                        lo[j8] = lw;
                    }
                    const int off = SWZ(n, sh2 * 32 + g * 16);
                    *(short8*)((char*)Sh + n * FSTRB + off) = hi;
                    *(short8*)((char*)Sl + n * FSTRB + off) = lo;
                }
            }
            __syncthreads();

            // ---- GEMM: wave wv owns m in {2wv, 2wv+1}, n in {0,1,2}
            {
                const int ko = lq * 16;   // byte offset in k (32 shorts/row)
                short8 ah[2], al[2];
                #pragma unroll
                for (int m2 = 0; m2 < 2; ++m2) {
                    const int row = (2 * wv + m2) * 16 + lr;
                    const int off = SWZ(row, ko);
                    ah[m2] = *(const short8*)((const char*)Fh + row * FSTRB + off);
                    al[m2] = *(const short8*)((const char*)Fl + row * FSTRB + off);
                }
                #pragma unroll
                for (int n = 0; n < 3; ++n) {
                    const int col = n * 16 + lr;
                    const int off = SWZ(col, ko);
                    short8 bh = *(const short8*)((const char*)Sh + col * FSTRB + off);
                    short8 bl = *(const short8*)((const char*)Sl + col * FSTRB + off);
                    #pragma unroll
                    for (int m2 = 0; m2 < 2; ++m2) {
                        acc[m2 * 3 + n] = __builtin_amdgcn_mfma_f32_16x16x32_bf16(
                                              ah[m2], bh, acc[m2 * 3 + n], 0, 0, 0);
                        acc[m2 * 3 + n] = __builtin_amdgcn_mfma_f32_16x16x32_bf16(
                                              ah[m2], bl, acc[m2 * 3 + n], 0, 0, 0);
                        acc[m2 * 3 + n] = __builtin_amdgcn_mfma_f32_16x16x32_bf16(
                                              al[m2], bh, acc[m2 * 3 + n], 0, 0, 0);
                    }
                }
            }
            if (ks < NSLICE - 1) __syncthreads();   // GEMM done before next build
        }

        // ---- epilogue: xx-contraction via verified DPP tree
        #pragma unroll
        for (int m2 = 0; m2 < 2; ++m2) {
            #pragma unroll
            for (int n = 0; n < 3; ++n) {
                const float v1x = U1[n * 16 + lr] * w1ec;
                #pragma unroll
                for (int reg = 0; reg < 4; ++reg) {
                    const int row = (2 * wv + m2) * 16 + lq * 4 + reg;
                    const float xmv = XL[row * ELL + lr];
                    float cv = (acc[m2 * 3 + n][reg] + v1x) * xmv;
                    cv = row16_sum(cv);
                    if (lr == 0) {
                        const int gslot = base + row;
                        if (gslot < cnt) {
                            const int b = list_g[e * B_ + gslot];
                            out[(size_t)b * (C_ * EQ) + c * EQ + n] = cv;
                        }
                    }
                }
            }
        }
    }
}

// ---------------------------------------------------------------------------
extern "C" void kernel_launch(void* const* d_in, const int* in_sizes, int n_in,
                              void* d_out, int out_size, void* d_ws, size_t ws_size,
                              hipStream_t stream) {
    const float* x    = (const float*)d_in[0];
    const float* y    = (const float*)d_in[1];
    const float* U3   = (const float*)d_in[2];
    const float* U2   = (const float*)d_in[3];
    const float* U1   = (const float*)d_in[4];
    const float* wmax = (const float*)d_in[5];
    const float* w2   = (const float*)d_in[6];
    const float* w1   = (const float*)d_in[7];
    float* out = (float*)d_out;
    char*  ws  = (char*)d_ws;

    int*   cnt_g  = (int*)(ws + 0);
    int*   list_g = (int*)(ws + 64);
    float* Sg     = (float*)(ws + 65536);
    (void)ws_size;   // 44.3 MB needed; harness ws confirmed >= 66 MB

    k_s<<<dim3(49, E_, 4), 256, 0, stream>>>(U3, U2, wmax, w2, y, Sg, cnt_g, list_g);
    k_main<<<dim3(C_, E_), 256, 0, stream>>>(x, Sg, U1, w1, cnt_g, list_g, out);
}